// Round 2
// baseline (4293.451 us; speedup 1.0000x reference)
//
#include <hip/hip_runtime.h>
#include <math.h>

// Problem constants (validated against in_sizes at launch)
// x[50000,128] w1[128,64] b1[64] w2[192,16] b2[16] lin_w[48,16] lin_b[16]
// edge_index[2,800000] edge_index2[2,3000000] (int32, row0=src, row1=dst)

// ---------------- GEMM1: HW1 = x @ w1  ([n,128]@[128,64]) ----------------
__global__ void k_gemm1(const float* __restrict__ x, const float* __restrict__ w1,
                        float* __restrict__ hw, int n) {
    __shared__ float ws[128 * 64];   // 32 KB
    __shared__ float xs[4 * 128];
    int t = threadIdx.x;
    for (int i = t; i < 128 * 64; i += 256) ws[i] = w1[i];
    int row0 = blockIdx.x * 4;
    for (int i = t; i < 4 * 128; i += 256) {
        int r = row0 + (i >> 7);
        xs[i] = (r < n) ? x[r * 128 + (i & 127)] : 0.f;
    }
    __syncthreads();
    int r = t >> 6, c = t & 63;
    int v = row0 + r;
    if (v >= n) return;
    float acc = 0.f;
    const float* xr = &xs[r * 128];
    #pragma unroll 8
    for (int k = 0; k < 128; ++k) acc += xr[k] * ws[k * 64 + c];
    hw[v * 64 + c] = acc;
}

// ---------------- degree / dinv ----------------
__global__ void k_degree(const int* __restrict__ dst, float* __restrict__ deg, int E) {
    int i = blockIdx.x * 256 + threadIdx.x;
    if (i < E) atomicAdd(&deg[dst[i]], 1.0f);
}

__global__ void k_dinv(const float* __restrict__ deg1, float* __restrict__ dinv1,
                       const float* __restrict__ deg2, float* __restrict__ dinv2, int n) {
    int i = blockIdx.x * 256 + threadIdx.x;
    if (i >= n) return;
    float d = deg1[i];
    dinv1[i] = (d > 0.f) ? rsqrtf(d) : 0.f;
    d = deg2[i];
    dinv2[i] = (d > 0.f) ? rsqrtf(d) : 0.f;
}

// ---- layer-1 scatter: acc[dst] += dinv[src]*HW1[src]  (64 feats) ----
// (dinv[dst] is applied ONCE in k_combine1 — factored normalization)
// 16 threads per edge, one float4 each
__global__ void k_scatter64(const int* __restrict__ src, const int* __restrict__ dst,
                            const float* __restrict__ dinv,
                            const float4* __restrict__ hw4,
                            float* __restrict__ acc, int E) {
    int tid = blockIdx.x * 256 + threadIdx.x;
    int e = tid >> 4, q = tid & 15;
    if (e >= E) return;
    int s = src[e], d = dst[e];
    float sc = dinv[s];
    float4 h = hw4[s * 16 + q];
    float* base = &acc[d * 64 + q * 4];
    atomicAdd(base + 0, h.x * sc);
    atomicAdd(base + 1, h.y * sc);
    atomicAdd(base + 2, h.z * sc);
    atomicAdd(base + 3, h.w * sc);
}

// ---------------- combine layer 1 -> R1[n,192] with bias+relu ----------------
__global__ void k_combine1(const float* __restrict__ hw, const float* __restrict__ acca,
                           const float* __restrict__ accb, const float* __restrict__ dinv1,
                           const float* __restrict__ dinv2, const float* __restrict__ b1,
                           float* __restrict__ R1, int n) {
    int idx = blockIdx.x * 256 + threadIdx.x;
    if (idx >= n * 64) return;
    int v = idx >> 6, f = idx & 63;
    float bb = b1[f];
    float a = fmaf(dinv1[v], acca[idx], bb); a = a > 0.f ? a : 0.f;
    float b = fmaf(dinv2[v], accb[idx], bb); b = b > 0.f ? b : 0.f;
    float c = hw[idx] + bb;                  c = c > 0.f ? c : 0.f;
    float* r = &R1[v * 192 + f];
    r[0]   = a;
    r[64]  = b;
    r[128] = c;
}

// ---------------- GEMM2: hw2 = R1 @ w2  ([n,192]@[192,16]) ----------------
__global__ void k_gemm2(const float* __restrict__ R1, const float* __restrict__ w2,
                        float* __restrict__ hw2, int n) {
    __shared__ float ws[192 * 16];    // 12 KB
    __shared__ float rs[16][193];     // padded: bank-conflict-free broadcast
    int t = threadIdx.x;
    for (int i = t; i < 192 * 16; i += 256) ws[i] = w2[i];
    int row0 = blockIdx.x * 16;
    for (int i = t; i < 16 * 192; i += 256) {
        int r = i / 192, j = i - r * 192;
        int v = row0 + r;
        rs[r][j] = (v < n) ? R1[v * 192 + j] : 0.f;
    }
    __syncthreads();
    int r = t >> 4, c = t & 15;
    int v = row0 + r;
    if (v >= n) return;
    float acc = 0.f;
    #pragma unroll 8
    for (int j = 0; j < 192; ++j) acc += rs[r][j] * ws[j * 16 + c];
    hw2[v * 16 + c] = acc;
}

// ---- layer-2 scatter: acc2[dst] += dinv[src]*hw2[src] (16 feats) ----
// (dinv[dst] applied once in k_final)
// 4 threads per edge, one float4 each
__global__ void k_scatter16(const int* __restrict__ src, const int* __restrict__ dst,
                            const float* __restrict__ dinv,
                            const float4* __restrict__ hw4,
                            float* __restrict__ acc, int E) {
    int tid = blockIdx.x * 256 + threadIdx.x;
    int e = tid >> 2, q = tid & 3;
    if (e >= E) return;
    int s = src[e], d = dst[e];
    float sc = dinv[s];
    float4 h = hw4[s * 4 + q];
    float* base = &acc[d * 16 + q * 4];
    atomicAdd(base + 0, h.x * sc);
    atomicAdd(base + 1, h.y * sc);
    atomicAdd(base + 2, h.z * sc);
    atomicAdd(base + 3, h.w * sc);
}

// ---------------- final: combine layer-2 branches, linear head, log_softmax ----------
__global__ void k_final(const float* __restrict__ hw2, const float* __restrict__ acc2a,
                        const float* __restrict__ acc2b, const float* __restrict__ dinv1,
                        const float* __restrict__ dinv2, const float* __restrict__ b2,
                        const float* __restrict__ lw, const float* __restrict__ lb,
                        float* __restrict__ out, int n) {
    __shared__ float lws[48 * 16];   // 3 KB
    __shared__ float r2s[16][49];    // padded
    int t = threadIdx.x;
    for (int i = t; i < 48 * 16; i += 256) lws[i] = lw[i];
    int ni = t >> 4, c = t & 15;
    int v = blockIdx.x * 16 + ni;
    if (v < n) {
        float bb = b2[c];
        r2s[ni][c]      = fmaf(dinv1[v], acc2a[v * 16 + c], bb);
        r2s[ni][16 + c] = fmaf(dinv2[v], acc2b[v * 16 + c], bb);
        r2s[ni][32 + c] = hw2[v * 16 + c] + bb;
    }
    __syncthreads();
    if (v >= n) return;
    float o = lb[c];
    #pragma unroll
    for (int j = 0; j < 48; ++j) o += r2s[ni][j] * lws[j * 16 + c];
    // log_softmax across the 16 lanes of this node's group (within one wave)
    float m = o;
    for (int off = 8; off >= 1; off >>= 1) m = fmaxf(m, __shfl_xor(m, off, 16));
    float e = expf(o - m);
    float ssum = e;
    for (int off = 8; off >= 1; off >>= 1) ssum += __shfl_xor(ssum, off, 16);
    out[v * 16 + c] = (o - m) - logf(ssum);
}

extern "C" void kernel_launch(void* const* d_in, const int* in_sizes, int n_in,
                              void* d_out, int out_size, void* d_ws, size_t ws_size,
                              hipStream_t stream) {
    const float* x     = (const float*)d_in[0];
    const float* w1    = (const float*)d_in[1];
    const float* b1    = (const float*)d_in[2];
    const float* w2    = (const float*)d_in[3];
    const float* b2    = (const float*)d_in[4];
    const float* lin_w = (const float*)d_in[5];
    const float* lin_b = (const float*)d_in[6];
    const int*   ei    = (const int*)d_in[7];
    const int*   ei2   = (const int*)d_in[8];

    const int n  = in_sizes[0] / 128;   // 50000
    const int E1 = in_sizes[7] / 2;     // 800000
    const int E2 = in_sizes[8] / 2;     // 3000000

    char* ws = (char*)d_ws;
    // workspace layout (bytes), all float4-aligned:
    float* hw    = (float*)(ws + 0);          // [n,64]  HW1, later reused as hw2 [n,16]
    float* acca  = (float*)(ws + 12800000);   // [n,64]  layer1 acc (edge set 1); later acc2a [n,16]
    float* accb  = (float*)(ws + 25600000);   // [n,64]  layer1 acc (edge set 2); later acc2b [n,16]
    float* R1    = (float*)(ws + 38400000);   // [n,192]
    float* deg1  = (float*)(ws + 76800000);   // [n]
    float* dinv1 = (float*)(ws + 77000000);   // [n]
    float* deg2  = (float*)(ws + 77200000);   // [n]
    float* dinv2 = (float*)(ws + 77400000);   // [n]

    hipMemsetAsync(acca, 0, (size_t)n * 64 * 4, stream);
    hipMemsetAsync(accb, 0, (size_t)n * 64 * 4, stream);
    hipMemsetAsync(deg1, 0, (size_t)n * 4, stream);
    hipMemsetAsync(deg2, 0, (size_t)n * 4, stream);

    k_gemm1<<<(n + 3) / 4, 256, 0, stream>>>(x, w1, hw, n);
    k_degree<<<(E1 + 255) / 256, 256, 0, stream>>>(ei + E1, deg1, E1);
    k_degree<<<(E2 + 255) / 256, 256, 0, stream>>>(ei2 + E2, deg2, E2);
    k_dinv<<<(n + 255) / 256, 256, 0, stream>>>(deg1, dinv1, deg2, dinv2, n);

    k_scatter64<<<(E1 * 16 + 255) / 256, 256, 0, stream>>>(ei, ei + E1, dinv1,
                                                           (const float4*)hw, acca, E1);
    k_scatter64<<<(E2 * 16 + 255) / 256, 256, 0, stream>>>(ei2, ei2 + E2, dinv2,
                                                           (const float4*)hw, accb, E2);

    k_combine1<<<(n * 64 + 255) / 256, 256, 0, stream>>>(hw, acca, accb, dinv1, dinv2,
                                                         b1, R1, n);

    k_gemm2<<<(n + 15) / 16, 256, 0, stream>>>(R1, w2, hw, n);  // hw now holds hw2 [n,16]

    hipMemsetAsync(acca, 0, (size_t)n * 16 * 4, stream);
    hipMemsetAsync(accb, 0, (size_t)n * 16 * 4, stream);

    k_scatter16<<<(E1 * 4 + 255) / 256, 256, 0, stream>>>(ei, ei + E1, dinv1,
                                                          (const float4*)hw, acca, E1);
    k_scatter16<<<(E2 * 4 + 255) / 256, 256, 0, stream>>>(ei2, ei2 + E2, dinv2,
                                                          (const float4*)hw, accb, E2);

    k_final<<<(n + 15) / 16, 256, 0, stream>>>(hw, acca, accb, dinv1, dinv2, b2,
                                               lin_w, lin_b, (float*)d_out, n);
}

// Round 3
// 847.673 us; speedup vs baseline: 5.0650x; 5.0650x over previous
//
#include <hip/hip_runtime.h>
#include <math.h>

// x[50000,128] w1[128,64] b1[64] w2[192,16] b2[16] lin_w[48,16] lin_b[16]
// edge_index[2,800000] edge_index2[2,3000000] (int32, row0=src, row1=dst)
//
// Strategy: no float atomics. Build CSR by dst per edge set (histogram +
// 1-block wave scan + atomic-cursor bucket), then gather-aggregate with
// register accumulation and fully-coalesced row reads (hw is LLC-resident).

// ---------------- GEMM1: HW1 = x @ w1  ([n,128]@[128,64]) ----------------
__global__ void k_gemm1(const float* __restrict__ x, const float* __restrict__ w1,
                        float* __restrict__ hw, int n) {
    __shared__ float ws[128 * 64];   // 32 KB
    __shared__ float xs[4 * 128];
    int t = threadIdx.x;
    for (int i = t; i < 128 * 64; i += 256) ws[i] = w1[i];
    int row0 = blockIdx.x * 4;
    for (int i = t; i < 4 * 128; i += 256) {
        int r = row0 + (i >> 7);
        xs[i] = (r < n) ? x[r * 128 + (i & 127)] : 0.f;
    }
    __syncthreads();
    int r = t >> 6, c = t & 63;
    int v = row0 + r;
    if (v >= n) return;
    float acc = 0.f;
    const float* xr = &xs[r * 128];
    #pragma unroll 8
    for (int k = 0; k < 128; ++k) acc += xr[k] * ws[k * 64 + c];
    hw[v * 64 + c] = acc;
}

// ---------------- degree histogram (int atomics) ----------------
__global__ void k_degree(const int* __restrict__ dst, int* __restrict__ deg, int E) {
    int i = blockIdx.x * 256 + threadIdx.x;
    if (i < E) atomicAdd(&deg[dst[i]], 1);
}

__global__ void k_dinv(const int* __restrict__ deg1, float* __restrict__ dinv1,
                       const int* __restrict__ deg2, float* __restrict__ dinv2, int n) {
    int i = blockIdx.x * 256 + threadIdx.x;
    if (i >= n) return;
    int d = deg1[i];
    dinv1[i] = (d > 0) ? rsqrtf((float)d) : 0.f;
    d = deg2[i];
    dinv2[i] = (d > 0) ? rsqrtf((float)d) : 0.f;
}

// ------- exclusive prefix scan of deg -> rowstart & cursor (2 blocks, one per set) ----
__global__ void __launch_bounds__(1024)
k_scan2(const int* __restrict__ dA, int* __restrict__ rsA, int* __restrict__ curA,
        const int* __restrict__ dB, int* __restrict__ rsB, int* __restrict__ curB, int n) {
    const int* deg = blockIdx.x ? dB : dA;
    int* rs  = blockIdx.x ? rsB : rsA;
    int* cur = blockIdx.x ? curB : curA;
    __shared__ int wsum[16];
    __shared__ int woff[16];
    __shared__ int chunk_tot;
    __shared__ int carry_s;
    int t = threadIdx.x, lane = t & 63, wid = t >> 6;
    if (t == 0) carry_s = 0;
    __syncthreads();
    for (int base = 0; base < n; base += 1024) {
        int i = base + t;
        int v = (i < n) ? deg[i] : 0;
        int incl = v;
        #pragma unroll
        for (int off = 1; off < 64; off <<= 1) {
            int tv = __shfl_up(incl, off, 64);
            if (lane >= off) incl += tv;
        }
        if (lane == 63) wsum[wid] = incl;
        __syncthreads();
        if (t < 16) {
            int wv = wsum[t];
            int winc = wv;
            #pragma unroll
            for (int off = 1; off < 16; off <<= 1) {
                int tv = __shfl_up(winc, off, 16);
                if (t >= off) winc += tv;
            }
            woff[t] = winc - wv;
            if (t == 15) chunk_tot = winc;
        }
        __syncthreads();
        int excl = incl - v + woff[wid] + carry_s;
        if (i < n) { rs[i] = excl; cur[i] = excl; }
        __syncthreads();
        if (t == 0) carry_s += chunk_tot;
        __syncthreads();
    }
    if (t == 0) rs[n] = carry_s;
}

// ------- bucket: sorted_src[pos] = src, pos = cursor[dst]++ ----------------
__global__ void k_bucket(const int* __restrict__ src, const int* __restrict__ dst,
                         int* __restrict__ cursor, int* __restrict__ ssrc, int E) {
    int i = blockIdx.x * 256 + threadIdx.x;
    if (i >= E) return;
    int d = dst[i];
    int pos = atomicAdd(&cursor[d], 1);
    ssrc[pos] = src[i];
}

// ------- layer-1 aggregate: 16 lanes/node, fused dinv[dst]*sum + bias + relu -> R1 ----
__global__ void k_agg64(const int* __restrict__ rowstart, const int* __restrict__ ssrc,
                        const float* __restrict__ dinv_src, const float* __restrict__ dinv_dst,
                        const float4* __restrict__ hw4, const float4* __restrict__ bias4,
                        float* __restrict__ R1, int col_off, int n) {
    int tid = blockIdx.x * 256 + threadIdx.x;
    int v = tid >> 4, q = tid & 15;
    if (v >= n) return;
    int beg = rowstart[v], end = rowstart[v + 1];
    float4 a = {0.f, 0.f, 0.f, 0.f};
    for (int i = beg; i < end; ++i) {
        int s = ssrc[i];
        float sc = dinv_src[s];
        float4 h = hw4[s * 16 + q];
        a.x += h.x * sc; a.y += h.y * sc; a.z += h.z * sc; a.w += h.w * sc;
    }
    float dd = dinv_dst[v];
    float4 bb = bias4[q];
    float4 o;
    o.x = fmaf(a.x, dd, bb.x); o.x = o.x > 0.f ? o.x : 0.f;
    o.y = fmaf(a.y, dd, bb.y); o.y = o.y > 0.f ? o.y : 0.f;
    o.z = fmaf(a.z, dd, bb.z); o.z = o.z > 0.f ? o.z : 0.f;
    o.w = fmaf(a.w, dd, bb.w); o.w = o.w > 0.f ? o.w : 0.f;
    *(float4*)&R1[v * 192 + col_off + q * 4] = o;
}

// ------- layer-1 self branch: R1[:,128:192] = relu(hw + b1) ----------------
__global__ void k_self64(const float* __restrict__ hw, const float* __restrict__ b1,
                         float* __restrict__ R1, int n) {
    int idx = blockIdx.x * 256 + threadIdx.x;
    if (idx >= n * 64) return;
    int v = idx >> 6, f = idx & 63;
    float c = hw[idx] + b1[f];
    R1[v * 192 + 128 + f] = c > 0.f ? c : 0.f;
}

// ---------------- GEMM2: hw2 = R1 @ w2  ([n,192]@[192,16]) ----------------
__global__ void k_gemm2(const float* __restrict__ R1, const float* __restrict__ w2,
                        float* __restrict__ hw2, int n) {
    __shared__ float ws[192 * 16];
    __shared__ float rs[16][193];
    int t = threadIdx.x;
    for (int i = t; i < 192 * 16; i += 256) ws[i] = w2[i];
    int row0 = blockIdx.x * 16;
    for (int i = t; i < 16 * 192; i += 256) {
        int r = i / 192, j = i - r * 192;
        int v = row0 + r;
        rs[r][j] = (v < n) ? R1[v * 192 + j] : 0.f;
    }
    __syncthreads();
    int r = t >> 4, c = t & 15;
    int v = row0 + r;
    if (v >= n) return;
    float acc = 0.f;
    #pragma unroll 8
    for (int j = 0; j < 192; ++j) acc += rs[r][j] * ws[j * 16 + c];
    hw2[v * 16 + c] = acc;
}

// ------- layer-2 aggregate: 4 lanes/node, raw sum of dinv[src]*hw2[src] ----
__global__ void k_agg16(const int* __restrict__ rowstart, const int* __restrict__ ssrc,
                        const float* __restrict__ dinv_src,
                        const float4* __restrict__ hw4, float* __restrict__ acc, int n) {
    int tid = blockIdx.x * 256 + threadIdx.x;
    int v = tid >> 2, q = tid & 3;
    if (v >= n) return;
    int beg = rowstart[v], end = rowstart[v + 1];
    float4 a = {0.f, 0.f, 0.f, 0.f};
    for (int i = beg; i < end; ++i) {
        int s = ssrc[i];
        float sc = dinv_src[s];
        float4 h = hw4[s * 4 + q];
        a.x += h.x * sc; a.y += h.y * sc; a.z += h.z * sc; a.w += h.w * sc;
    }
    *(float4*)&acc[v * 16 + q * 4] = a;
}

// ------- final: combine layer-2 branches, linear head, log_softmax ----------
__global__ void k_final(const float* __restrict__ hw2, const float* __restrict__ acc2a,
                        const float* __restrict__ acc2b, const float* __restrict__ dinv1,
                        const float* __restrict__ dinv2, const float* __restrict__ b2,
                        const float* __restrict__ lw, const float* __restrict__ lb,
                        float* __restrict__ out, int n) {
    __shared__ float lws[48 * 16];
    __shared__ float r2s[16][49];
    int t = threadIdx.x;
    for (int i = t; i < 48 * 16; i += 256) lws[i] = lw[i];
    int ni = t >> 4, c = t & 15;
    int v = blockIdx.x * 16 + ni;
    if (v < n) {
        float bb = b2[c];
        r2s[ni][c]      = fmaf(dinv1[v], acc2a[v * 16 + c], bb);
        r2s[ni][16 + c] = fmaf(dinv2[v], acc2b[v * 16 + c], bb);
        r2s[ni][32 + c] = hw2[v * 16 + c] + bb;
    }
    __syncthreads();
    if (v >= n) return;
    float o = lb[c];
    #pragma unroll
    for (int j = 0; j < 48; ++j) o += r2s[ni][j] * lws[j * 16 + c];
    float m = o;
    for (int off = 8; off >= 1; off >>= 1) m = fmaxf(m, __shfl_xor(m, off, 16));
    float e = expf(o - m);
    float ssum = e;
    for (int off = 8; off >= 1; off >>= 1) ssum += __shfl_xor(ssum, off, 16);
    out[v * 16 + c] = (o - m) - logf(ssum);
}

extern "C" void kernel_launch(void* const* d_in, const int* in_sizes, int n_in,
                              void* d_out, int out_size, void* d_ws, size_t ws_size,
                              hipStream_t stream) {
    const float* x     = (const float*)d_in[0];
    const float* w1    = (const float*)d_in[1];
    const float* b1    = (const float*)d_in[2];
    const float* w2    = (const float*)d_in[3];
    const float* b2    = (const float*)d_in[4];
    const float* lin_w = (const float*)d_in[5];
    const float* lin_b = (const float*)d_in[6];
    const int*   ei    = (const int*)d_in[7];
    const int*   ei2   = (const int*)d_in[8];

    const int n  = in_sizes[0] / 128;   // 50000
    const int E1 = in_sizes[7] / 2;     // 800000
    const int E2 = in_sizes[8] / 2;     // 3000000

    char* ws = (char*)d_ws;
    // workspace layout (bytes):
    float* hw    = (float*)(ws + 0);           // [n,64] HW1; later hw2 [n,16]
    float* R1    = (float*)(ws + 12800000);    // [n,192]
    int*   ssrc1 = (int*)  (ws + 51200000);    // [E1]
    int*   ssrc2 = (int*)  (ws + 54400000);    // [E2]
    float* acc2a = (float*)(ws + 66400000);    // [n,16]
    float* acc2b = (float*)(ws + 69600000);    // [n,16]
    int*   deg1  = (int*)  (ws + 72800000);    // [n]
    int*   deg2  = (int*)  (ws + 73000000);    // [n]
    float* dinv1 = (float*)(ws + 73200000);    // [n]
    float* dinv2 = (float*)(ws + 73400000);    // [n]
    int*   rs1   = (int*)  (ws + 73600000);    // [n+1]
    int*   rs2   = (int*)  (ws + 73800016);    // [n+1]
    int*   cur1  = (int*)  (ws + 74000032);    // [n]
    int*   cur2  = (int*)  (ws + 74200032);    // [n]

    hipMemsetAsync(deg1, 0, (size_t)n * 4, stream);
    hipMemsetAsync(deg2, 0, (size_t)n * 4, stream);

    k_gemm1<<<(n + 3) / 4, 256, 0, stream>>>(x, w1, hw, n);

    k_degree<<<(E1 + 255) / 256, 256, 0, stream>>>(ei + E1, deg1, E1);
    k_degree<<<(E2 + 255) / 256, 256, 0, stream>>>(ei2 + E2, deg2, E2);
    k_dinv<<<(n + 255) / 256, 256, 0, stream>>>(deg1, dinv1, deg2, dinv2, n);
    k_scan2<<<2, 1024, 0, stream>>>(deg1, rs1, cur1, deg2, rs2, cur2, n);
    k_bucket<<<(E1 + 255) / 256, 256, 0, stream>>>(ei, ei + E1, cur1, ssrc1, E1);
    k_bucket<<<(E2 + 255) / 256, 256, 0, stream>>>(ei2, ei2 + E2, cur2, ssrc2, E2);

    k_agg64<<<(n * 16 + 255) / 256, 256, 0, stream>>>(rs1, ssrc1, dinv1, dinv1,
                                                      (const float4*)hw, (const float4*)b1,
                                                      R1, 0, n);
    k_agg64<<<(n * 16 + 255) / 256, 256, 0, stream>>>(rs2, ssrc2, dinv2, dinv2,
                                                      (const float4*)hw, (const float4*)b1,
                                                      R1, 64, n);
    k_self64<<<(n * 64 + 255) / 256, 256, 0, stream>>>(hw, b1, R1, n);

    k_gemm2<<<(n + 15) / 16, 256, 0, stream>>>(R1, w2, hw, n);  // hw := hw2 [n,16]

    k_agg16<<<(n * 4 + 255) / 256, 256, 0, stream>>>(rs1, ssrc1, dinv1,
                                                     (const float4*)hw, acc2a, n);
    k_agg16<<<(n * 4 + 255) / 256, 256, 0, stream>>>(rs2, ssrc2, dinv2,
                                                     (const float4*)hw, acc2b, n);

    k_final<<<(n + 15) / 16, 256, 0, stream>>>(hw, acc2a, acc2b, dinv1, dinv2, b2,
                                               lin_w, lin_b, (float*)d_out, n);
}